// Round 1
// baseline (114.130 us; speedup 1.0000x reference)
//
#include <hip/hip_runtime.h>
#include <math.h>

#define NCLUST   64
#define CDIM     256
#define TOKDIM   256
#define DD       768
#define HDIM     512
#define LOCALDIM (NCLUST * CDIM)      // 16384
#define FEATDIM  (LOCALDIM + TOKDIM)  // 16640
#define BB       64
#define THRESH   0.7f

// Kernel 1: per-batch global MLP + feats row write.
// local part of feats is exactly 1/norm (softmax(axis=1).sum(axis=1) == 1).
__global__ __launch_bounds__(256) void mlpg_kernel(
    const float* __restrict__ gtok,                       // [B, 768]
    const float* __restrict__ W1, const float* __restrict__ b1,   // [768,512],[512]
    const float* __restrict__ W2, const float* __restrict__ b2,   // [512,256],[256]
    float* __restrict__ feats)                            // [B, 16640]
{
    __shared__ float xs[DD];
    __shared__ float hs[HDIM];
    __shared__ float red[4];
    const int b = blockIdx.x, t = threadIdx.x;

    for (int i = t; i < DD; i += 256) xs[i] = gtok[b * DD + i];
    __syncthreads();

    // hidden layer: each thread computes 2 of 512 units
    float h0 = b1[t], h1 = b1[t + 256];
    #pragma unroll 4
    for (int d = 0; d < DD; ++d) {
        const float x = xs[d];
        h0 = fmaf(x, W1[d * HDIM + t], h0);
        h1 = fmaf(x, W1[d * HDIM + t + 256], h1);
    }
    hs[t]       = fmaxf(h0, 0.f);
    hs[t + 256] = fmaxf(h1, 0.f);
    __syncthreads();

    // output layer: each thread computes 1 of 256 outputs
    float g = b2[t];
    #pragma unroll 4
    for (int j = 0; j < HDIM; ++j)
        g = fmaf(hs[j], W2[j * TOKDIM + t], g);

    // block reduction of ||g||^2 (4 waves of 64)
    float s = g * g;
    #pragma unroll
    for (int off = 32; off > 0; off >>= 1) s += __shfl_down(s, off);
    if ((t & 63) == 0) red[t >> 6] = s;
    __syncthreads();
    const float ssq  = red[0] + red[1] + red[2] + red[3];
    const float norm = sqrtf((float)LOCALDIM + ssq);   // local part contributes 16384 * 1^2
    const float inv  = 1.f / fmaxf(norm, 1e-12f);

    float* frow = feats + (size_t)b * FEATDIM;
    const float4 v4 = make_float4(inv, inv, inv, inv);
    float4* f4 = (float4*)frow;
    for (int i = t; i < LOCALDIM / 4; i += 256) f4[i] = v4;   // coalesced float4 fill
    frow[LOCALDIM + t] = g * inv;
}

// Kernel 2: 64x64 covisibility mask from feats.
// sim_ij = 16384*inv_i*inv_j + dot(gn_i, gn_j); feats[b][0] == inv_b.
__global__ __launch_bounds__(1024) void mask_kernel(
    const float* __restrict__ feats, float* __restrict__ mask,
    const int* __restrict__ kptr)
{
    __shared__ float gnT[TOKDIM][BB];   // transposed: [d][j] -> conflict-free dot reads
    __shared__ float sim[BB][BB + 1];   // +1 pad: conflict-free column reads in top-k
    __shared__ float invn[BB];
    __shared__ unsigned long long forced[BB];
    const int t = threadIdx.x;

    for (int i = t; i < BB * TOKDIM; i += 1024) {
        const int j = i >> 8, d = i & 255;           // coalesced global read
        gnT[d][j] = feats[(size_t)j * FEATDIM + LOCALDIM + d];
    }
    if (t < BB) { invn[t] = feats[(size_t)t * FEATDIM]; forced[t] = 1ull << t; } // diag
    __syncthreads();

    for (int e = t; e < BB * BB; e += 1024) {
        const int i = e >> 6, j = e & 63;            // per wave: i fixed, j = lane
        float s = (float)LOCALDIM * invn[i] * invn[j];
        #pragma unroll 8
        for (int d = 0; d < TOKDIM; ++d)
            s = fmaf(gnT[d][i], gnT[d][j], s);       // broadcast * stride-1
        sim[i][j] = s;
    }
    __syncthreads();

    int k = *kptr; if (k > BB) k = BB;
    if (t < BB) {
        // top-k selection, ties -> lowest index (matches jax.lax.top_k stability)
        unsigned long long used = 0;
        for (int p = 0; p < k; ++p) {
            float best = -INFINITY; int bi = -1;
            for (int j = 0; j < BB; ++j) {
                if ((used >> j) & 1ull) continue;
                const float v = sim[t][j];
                if (v > best) { best = v; bi = j; }
            }
            if (bi < 0) break;
            used |= 1ull << bi;
            atomicOr(&forced[bi], 1ull << t);        // mask[idx, row] = 1
        }
        atomicOr(&forced[t], used);                  // mask[row, idx] = 1
    }
    __syncthreads();

    for (int e = t; e < BB * BB; e += 1024) {
        const int i = e >> 6, j = e & 63;
        mask[e] = ((sim[i][j] > THRESH) || ((forced[i] >> j) & 1ull)) ? 1.f : 0.f;
    }
}

extern "C" void kernel_launch(void* const* d_in, const int* in_sizes, int n_in,
                              void* d_out, int out_size, void* d_ws, size_t ws_size,
                              hipStream_t stream) {
    // input order: local_features(0), global_token(1), W1_local(2), b1_local(3),
    // W2_local(4), b2_local(5), W1_global(6), b1_global(7), W2_global(8),
    // b2_global(9), k_nearest(10)
    const float* gtok = (const float*)d_in[1];
    const float* W1g  = (const float*)d_in[6];
    const float* b1g  = (const float*)d_in[7];
    const float* W2g  = (const float*)d_in[8];
    const float* b2g  = (const float*)d_in[9];
    const int*   kp   = (const int*)d_in[10];

    float* feats = (float*)d_out;                     // [64, 16640]
    float* mask  = feats + (size_t)BB * FEATDIM;      // [64, 64]

    hipLaunchKernelGGL(mlpg_kernel, dim3(BB), dim3(256), 0, stream,
                       gtok, W1g, b1g, W2g, b2g, feats);
    hipLaunchKernelGGL(mask_kernel, dim3(1), dim3(1024), 0, stream,
                       feats, mask, kp);
}

// Round 2
// 58.091 us; speedup vs baseline: 1.9647x; 1.9647x over previous
//
#include <hip/hip_runtime.h>
#include <math.h>

#define TOKDIM   256
#define DD       768
#define HDIM     512
#define LOCALDIM 16384
#define FEATDIM  16640            // 16384 + 256
#define BB       64
#define THRESH   0.7f

#define C1 8                      // layer-1 reduction chunks (768/8 = 96)
#define D1 96
#define C2 8                      // layer-2 reduction chunks (512/8 = 64)
#define D2 64

// workspace layout (float offsets)
#define WS_PH   0                           // [C1][64][512]  partial hidden
#define WS_PG   (C1*BB*HDIM)                // [C2][64][256]  partial g
#define WS_INV  (WS_PG + C2*BB*TOKDIM)      // [64]           1/norm
#define WS_GNT  (WS_INV + BB)               // [256][64]      gn transposed
#define WS_SIM  (WS_GNT + TOKDIM*BB)        // [64][64]       similarity

// K1: partial hidden sums. grid 512 = (b=64) x (c=8); thread t does units t, t+256
// over 96 of the 768 reduction dims. Coalesced W1 reads, 96-iter chains.
__global__ __launch_bounds__(256) void k1_hidden_partial(
    const float* __restrict__ gtok, const float* __restrict__ W1,
    float* __restrict__ ws)
{
    __shared__ float xs[D1];
    const int b = blockIdx.x >> 3, c = blockIdx.x & 7, t = threadIdx.x;
    if (t < D1) xs[t] = gtok[b * DD + c * D1 + t];
    __syncthreads();
    float h0 = 0.f, h1 = 0.f;
    const float* w = W1 + (size_t)(c * D1) * HDIM + t;
    #pragma unroll 8
    for (int d = 0; d < D1; ++d) {
        const float x = xs[d];
        h0 = fmaf(x, w[0],   h0);
        h1 = fmaf(x, w[256], h1);
        w += HDIM;
    }
    float* ph = ws + WS_PH + ((size_t)c * BB + b) * HDIM;
    ph[t] = h0; ph[t + 256] = h1;
}

// K2: fused h-reduce+bias+ReLU (staging) then partial g sums.
// grid 512 = (b=64) x (c=8); 64-iter chains over W2.
__global__ __launch_bounds__(256) void k2_out_partial(
    const float* __restrict__ b1, const float* __restrict__ W2,
    float* __restrict__ ws)
{
    __shared__ float hs[D2];
    const int b = blockIdx.x >> 3, c = blockIdx.x & 7, t = threadIdx.x;
    if (t < D2) {
        const int u = c * D2 + t;
        float s = b1[u];
        const float* ph = ws + WS_PH + (size_t)b * HDIM + u;
        #pragma unroll
        for (int cc = 0; cc < C1; ++cc) s += ph[(size_t)cc * BB * HDIM];
        hs[t] = fmaxf(s, 0.f);
    }
    __syncthreads();
    float s = 0.f;
    const float* w = W2 + (size_t)(c * D2) * TOKDIM + t;
    #pragma unroll 8
    for (int j = 0; j < D2; ++j) { s = fmaf(hs[j], w[0], s); w += TOKDIM; }
    ws[WS_PG + ((size_t)c * BB + b) * TOKDIM + t] = s;
}

// K3: finalize g, compute inv-norm, write normalized global part of feats,
// store gn transposed + inv into ws. grid 64.
__global__ __launch_bounds__(256) void k3_finalize(
    const float* __restrict__ b2, float* __restrict__ ws,
    float* __restrict__ feats)
{
    __shared__ float red[4];
    const int b = blockIdx.x, t = threadIdx.x;
    float g = b2[t];
    #pragma unroll
    for (int c = 0; c < C2; ++c) g += ws[WS_PG + ((size_t)c * BB + b) * TOKDIM + t];
    float s = g * g;
    #pragma unroll
    for (int off = 32; off > 0; off >>= 1) s += __shfl_down(s, off);
    if ((t & 63) == 0) red[t >> 6] = s;
    __syncthreads();
    const float ssq  = red[0] + red[1] + red[2] + red[3];
    const float inv  = 1.f / fmaxf(sqrtf((float)LOCALDIM + ssq), 1e-12f);
    const float gn   = g * inv;
    feats[(size_t)b * FEATDIM + LOCALDIM + t] = gn;
    ws[WS_GNT + (size_t)t * BB + b] = gn;
    if (t == 0) ws[WS_INV + b] = inv;
}

// K4: fill local part of feats (16384 copies of inv per row) at full chip width.
// grid 1024 x 256 = 262144 float4 stores.
__global__ __launch_bounds__(256) void k4_fill(
    const float* __restrict__ ws, float* __restrict__ feats)
{
    const int tid = blockIdx.x * 256 + threadIdx.x;   // 0..262143
    const int b = tid >> 12, off = tid & 4095;        // 4096 float4 per row
    const float inv = ws[WS_INV + b];
    ((float4*)feats)[(size_t)b * (FEATDIM / 4) + off] = make_float4(inv, inv, inv, inv);
}

// K5: sim row per block. gi in LDS (broadcast), gnT in ws (coalesced, L2-hot).
__global__ __launch_bounds__(256) void k5_sim(
    const float* __restrict__ feats, float* __restrict__ ws)
{
    __shared__ float gi[TOKDIM];
    __shared__ float part[4][BB];
    const int i = blockIdx.x, t = threadIdx.x;
    gi[t] = feats[(size_t)i * FEATDIM + LOCALDIM + t];
    __syncthreads();
    const int q = t >> 6, j = t & 63;
    float s = 0.f;
    const float* gT = ws + WS_GNT + (size_t)(q * 64) * BB + j;
    #pragma unroll 8
    for (int d = 0; d < 64; ++d) { s = fmaf(gi[q * 64 + d], gT[0], s); gT += BB; }
    part[q][j] = s;
    __syncthreads();
    if (t < BB) {
        const float invi = ws[WS_INV + i], invj = ws[WS_INV + t];
        const float dot = part[0][t] + part[1][t] + part[2][t] + part[3][t];
        ws[WS_SIM + i * BB + t] = (float)LOCALDIM * invi * invj + dot;
    }
}

// K6: top-k + threshold -> mask. Only truly serial part; 1 block.
__global__ __launch_bounds__(256) void k6_mask(
    const float* __restrict__ ws, float* __restrict__ mask,
    const int* __restrict__ kptr)
{
    __shared__ float sim[BB][BB + 1];     // +1 pad: conflict-free row scans
    __shared__ unsigned long long forced[BB];
    const int t = threadIdx.x;
    for (int e = t; e < BB * BB; e += 256) sim[e >> 6][e & 63] = ws[WS_SIM + e];
    if (t < BB) forced[t] = 1ull << t;    // diagonal
    __syncthreads();
    int k = *kptr; if (k > BB) k = BB;
    if (t < BB) {
        // top-k, ties -> lowest index (matches jax.lax.top_k stability)
        unsigned long long used = 0;
        for (int p = 0; p < k; ++p) {
            float best = -INFINITY; int bi = -1;
            for (int j = 0; j < BB; ++j) {
                if ((used >> j) & 1ull) continue;
                const float v = sim[t][j];
                if (v > best) { best = v; bi = j; }
            }
            if (bi < 0) break;
            used |= 1ull << bi;
            atomicOr(&forced[bi], 1ull << t);   // mask[idx, row] = 1
        }
        atomicOr(&forced[t], used);             // mask[row, idx] = 1
    }
    __syncthreads();
    for (int e = t; e < BB * BB; e += 256) {
        const int i = e >> 6, j = e & 63;
        mask[e] = ((sim[i][j] > THRESH) || ((forced[i] >> j) & 1ull)) ? 1.f : 0.f;
    }
}

extern "C" void kernel_launch(void* const* d_in, const int* in_sizes, int n_in,
                              void* d_out, int out_size, void* d_ws, size_t ws_size,
                              hipStream_t stream) {
    const float* gtok = (const float*)d_in[1];
    const float* W1g  = (const float*)d_in[6];
    const float* b1g  = (const float*)d_in[7];
    const float* W2g  = (const float*)d_in[8];
    const float* b2g  = (const float*)d_in[9];
    const int*   kp   = (const int*)d_in[10];

    float* feats = (float*)d_out;                     // [64, 16640]
    float* mask  = feats + (size_t)BB * FEATDIM;      // [64, 64]
    float* ws    = (float*)d_ws;

    hipLaunchKernelGGL(k1_hidden_partial, dim3(512),  dim3(256), 0, stream, gtok, W1g, ws);
    hipLaunchKernelGGL(k2_out_partial,    dim3(512),  dim3(256), 0, stream, b1g, W2g, ws);
    hipLaunchKernelGGL(k3_finalize,       dim3(BB),   dim3(256), 0, stream, b2g, ws, feats);
    hipLaunchKernelGGL(k4_fill,           dim3(1024), dim3(256), 0, stream, ws, feats);
    hipLaunchKernelGGL(k5_sim,            dim3(BB),   dim3(256), 0, stream, feats, ws);
    hipLaunchKernelGGL(k6_mask,           dim3(1),    dim3(256), 0, stream, ws, mask, kp);
}